// Round 5
// baseline (314.475 us; speedup 1.0000x reference)
//
#include <hip/hip_runtime.h>
#include <hip/hip_bf16.h>
#include <stdint.h>

// out = x @ (W_shared + W_expert)^T + bias   (MoE collapses: positional routing,
// shared expert weights, normalized top-2 gate weights sum to 1)
static constexpr int Mdim = 16384;  // T = B*N tokens
static constexpr int Ndim = 1024;
static constexpr int Kdim = 1024;
static constexpr int BM = 128, BN = 128;
static constexpr int PK = 128;          // K per B-panel phase (32 KiB LDS)
static constexpr int NPH = Kdim / PK;   // 8 phases
static constexpr int KS = PK / 32;      // 4 barrier-free ksteps per phase

typedef __attribute__((ext_vector_type(8))) __bf16 bf16x8;
typedef __attribute__((ext_vector_type(4))) float f32x4;
typedef __attribute__((ext_vector_type(8))) unsigned short ushort8;
typedef __attribute__((ext_vector_type(4))) unsigned int uint4v;

__device__ inline unsigned short f2bf_rn(float f) {
    union { float f; uint32_t u; } v; v.f = f;
    uint32_t u = v.u;
    uint32_t r = u + 0x7FFFu + ((u >> 16) & 1u);
    return (unsigned short)(r >> 16);
}

// pack bf16(a) | bf16(b)<<16, round-half-up: 2 adds + 1 v_perm (CK idiom)
__device__ inline unsigned int pkbf(float a, float b) {
    union { float f; uint32_t u; } ua, ub;
    ua.f = a; ub.f = b;
    return __builtin_amdgcn_perm(ub.u + 0x8000u, ua.u + 0x8000u, 0x07060302u);
}

// Wc = bf16(W_shared + W_expert), 8 elems/thread
__global__ __launch_bounds__(256) void cvt_w_kernel(const float* __restrict__ ws,
                                                    const float* __restrict__ we,
                                                    unsigned short* __restrict__ wc) {
    const size_t i = ((size_t)blockIdx.x * 256 + threadIdx.x) * 8;
    const f32x4* p0 = (const f32x4*)(ws + i);
    const f32x4* p1 = (const f32x4*)(we + i);
    f32x4 a0 = p0[0], a1 = p0[1], b0 = p1[0], b1 = p1[1];
    ushort8 o;
    o[0] = f2bf_rn(a0[0] + b0[0]); o[1] = f2bf_rn(a0[1] + b0[1]);
    o[2] = f2bf_rn(a0[2] + b0[2]); o[3] = f2bf_rn(a0[3] + b0[3]);
    o[4] = f2bf_rn(a1[0] + b1[0]); o[5] = f2bf_rn(a1[1] + b1[1]);
    o[6] = f2bf_rn(a1[2] + b1[2]); o[7] = f2bf_rn(a1[3] + b1[3]);
    *(ushort8*)(wc + i) = o;
}

__device__ inline void gload16(const void* g, void* l) {
    __builtin_amdgcn_global_load_lds((const __attribute__((address_space(1))) void*)g,
                                     (__attribute__((address_space(3))) void*)l,
                                     16, 0, 0);
}

// B-panel-resident GEMM. Per block (128m x 128n):
//  - B panel (128n x 128k bf16, 32 KiB) staged per phase via global_load_lds
//    (proven round-1 chunk pattern per 32k sub-tile). W is reused by 128
//    bm-blocks; LDS residency makes it immune to L2 thrash (round-4 bug).
//  - A (fp32 x, streamed once) is loaded per-kstep straight into VGPRs with
//    per-lane fragment addresses, converted fp32->bf16 in-register (v_perm
//    pack), NO LDS and no barrier -> the 4-kstep inner loop is barrier-free
//    and A loads pipeline across ksteps with fine-grained vmcnt.
//  - 2 barriers per phase, 16 total (vs 64 in the barrier-per-kstep shape).
// Wave tile 64x64 (4x4 MFMA tiles); explicit distance-1 A prefetch with
// compile-time double-buffer indices (fully unrolled: no scratch demotion).
__global__ __launch_bounds__(256, 3) void gemm_bstream(const float* __restrict__ X,
                                                       const unsigned short* __restrict__ Bt,
                                                       const float* __restrict__ bias,
                                                       float* __restrict__ C) {
    __shared__ unsigned short Bs[KS][BN * 32];  // 4 sub-tiles x 8 KiB = 32 KiB

    const int tid = threadIdx.x;
    const int wave = tid >> 6;
    const int lane = tid & 63;
    const int bid = blockIdx.x;
    const int bm = bid & 127;   // bm-fastest: the 8 bn-sharers of an X-stripe share an XCD
    const int bn = bid >> 7;
    const int wm = (wave >> 1) * 64;
    const int wn = (wave & 1) * 64;
    const int fr = lane & 15;
    const int fq = lane >> 4;

    // ---- B staging map (per 32k sub-tile: proven chunk pattern) ----
    const int cw0 = wave, cw1 = wave + 4;      // 1-KiB chunks = 16 rows
    const int brow0 = cw0 * 16 + (lane >> 2);
    const int brow1 = cw1 * 16 + (lane >> 2);
    const int bcol = (lane & 3) * 8;
    const unsigned short* gB0 = Bt + (size_t)(bn * BN + brow0) * Kdim + bcol;
    const unsigned short* gB1 = Bt + (size_t)(bn * BN + brow1) * Kdim + bcol;
    unsigned short* lB0 = &Bs[0][cw0 * 512 + lane * 8];
    unsigned short* lB1 = &Bs[0][cw1 * 512 + lane * 8];

    // ---- A fragment bases: frag i -> row bm*128+wm+i*16+fr, k base fq*8 ----
    const float* gA[4];
#pragma unroll
    for (int i = 0; i < 4; ++i)
        gA[i] = X + (size_t)(bm * BM + wm + i * 16 + fr) * Kdim + fq * 8;

    f32x4 acc[4][4] = {};
    f32x4 av[2][4][2];  // [buf][frag][half] — indexed only by unrolled constants

    for (int p = 0; p < NPH; ++p) {
        // A loads for kstep 0 fly while the block converges on the barrier
#pragma unroll
        for (int i = 0; i < 4; ++i) {
            const float* src = gA[i] + p * PK;
            av[0][i][0] = *(const f32x4*)(src);
            av[0][i][1] = *(const f32x4*)(src + 4);
        }
        __syncthreads();  // all waves done reading panel p-1
#pragma unroll
        for (int s = 0; s < KS; ++s) {
            gload16(gB0 + p * PK + s * 32, lB0 + s * 4096);
            gload16(gB1 + p * PK + s * 32, lB1 + s * 4096);
        }
        __syncthreads();  // drains B DMA (and av[0], already ~arrived)

#pragma unroll
        for (int s = 0; s < KS; ++s) {
            if (s + 1 < KS) {  // distance-1 prefetch of next kstep's A frags
#pragma unroll
                for (int i = 0; i < 4; ++i) {
                    const float* src = gA[i] + p * PK + (s + 1) * 32;
                    av[(s + 1) & 1][i][0] = *(const f32x4*)(src);
                    av[(s + 1) & 1][i][1] = *(const f32x4*)(src + 4);
                }
            }
            bf16x8 af[4], bfr[4];
#pragma unroll
            for (int i = 0; i < 4; ++i) {
                uint4v c;
                c.x = pkbf(av[s & 1][i][0][0], av[s & 1][i][0][1]);
                c.y = pkbf(av[s & 1][i][0][2], av[s & 1][i][0][3]);
                c.z = pkbf(av[s & 1][i][1][0], av[s & 1][i][1][1]);
                c.w = pkbf(av[s & 1][i][1][2], av[s & 1][i][1][3]);
                union { uint4v u; bf16x8 v; } cv; cv.u = c;
                af[i] = cv.v;
            }
#pragma unroll
            for (int j = 0; j < 4; ++j)
                bfr[j] = *(const bf16x8*)&Bs[s][(wn + j * 16 + fr) * 32 + fq * 8];
#pragma unroll
            for (int i = 0; i < 4; ++i)
#pragma unroll
                for (int j = 0; j < 4; ++j)
                    acc[i][j] = __builtin_amdgcn_mfma_f32_16x16x32_bf16(af[i], bfr[j], acc[i][j], 0, 0, 0);
        }
    }

    // Epilogue: C/D layout col = lane&15, row = (lane>>4)*4 + reg  [m89-verified]
#pragma unroll
    for (int j = 0; j < 4; ++j) {
        const int col = bn * BN + wn + j * 16 + fr;
        const float bv = bias[col];
#pragma unroll
        for (int i = 0; i < 4; ++i) {
            const int row = bm * BM + wm + i * 16 + fq * 4;
            float* pc = C + (size_t)row * Ndim + col;
#pragma unroll
            for (int r = 0; r < 4; ++r)
                pc[(size_t)r * Ndim] = acc[i][j][r] + bv;
        }
    }
}

extern "C" void kernel_launch(void* const* d_in, const int* in_sizes, int n_in,
                              void* d_out, int out_size, void* d_ws, size_t ws_size,
                              hipStream_t stream) {
    // inputs: x, cond, mask, W_shared, W_expert, W_gate, bias
    const float* x    = (const float*)d_in[0];
    const float* Wsh  = (const float*)d_in[3];
    const float* Wex  = (const float*)d_in[4];
    const float* bias = (const float*)d_in[6];
    float* out = (float*)d_out;

    unsigned short* Wbf = (unsigned short*)d_ws;  // 1024*1024 bf16 = 2 MiB

    hipLaunchKernelGGL(cvt_w_kernel, dim3((Ndim * Kdim) / (256 * 8)), dim3(256), 0, stream,
                       Wsh, Wex, Wbf);
    hipLaunchKernelGGL(gemm_bstream, dim3((Mdim / BM) * (Ndim / BN)), dim3(256), 0, stream,
                       x, Wbf, bias, out);
}

// Round 6
// 213.217 us; speedup vs baseline: 1.4749x; 1.4749x over previous
//
#include <hip/hip_runtime.h>
#include <hip/hip_bf16.h>
#include <stdint.h>

// out = x @ (W_shared + W_expert)^T + bias   (MoE collapses: positional routing,
// shared expert weights, normalized top-2 gate weights sum to 1)
static constexpr int Mdim = 16384;  // T = B*N tokens
static constexpr int Ndim = 1024;
static constexpr int Kdim = 1024;
static constexpr int BM = 128, BN = 128, BK = 32;
static constexpr int NT = Kdim / BK;  // 32 k-tiles

typedef __attribute__((ext_vector_type(8))) __bf16 bf16x8;
typedef __attribute__((ext_vector_type(4))) float f32x4;
typedef __attribute__((ext_vector_type(8))) unsigned short ushort8;

__device__ inline unsigned short f2bf_rn(float f) {
    union { float f; uint32_t u; } v; v.f = f;
    uint32_t u = v.u;
    uint32_t r = u + 0x7FFFu + ((u >> 16) & 1u);
    return (unsigned short)(r >> 16);
}

// pack bf16(a) | bf16(b)<<16, round-half-up: 2 adds + 1 v_perm
__device__ inline unsigned int pkbf(float a, float b) {
    union { float f; uint32_t u; } ua, ub;
    ua.f = a; ub.f = b;
    return __builtin_amdgcn_perm(ub.u + 0x8000u, ua.u + 0x8000u, 0x07060302u);
}

// Wc = bf16(W_shared + W_expert), 8 elems/thread
__global__ __launch_bounds__(256) void cvt_w_kernel(const float* __restrict__ ws,
                                                    const float* __restrict__ we,
                                                    unsigned short* __restrict__ wc) {
    const size_t i = ((size_t)blockIdx.x * 256 + threadIdx.x) * 8;
    const f32x4* p0 = (const f32x4*)(ws + i);
    const f32x4* p1 = (const f32x4*)(we + i);
    f32x4 a0 = p0[0], a1 = p0[1], b0 = p1[0], b1 = p1[1];
    ushort8 o;
    o[0] = f2bf_rn(a0[0] + b0[0]); o[1] = f2bf_rn(a0[1] + b0[1]);
    o[2] = f2bf_rn(a0[2] + b0[2]); o[3] = f2bf_rn(a0[3] + b0[3]);
    o[4] = f2bf_rn(a1[0] + b1[0]); o[5] = f2bf_rn(a1[1] + b1[1]);
    o[6] = f2bf_rn(a1[2] + b1[2]); o[7] = f2bf_rn(a1[3] + b1[3]);
    *(ushort8*)(wc + i) = o;
}

__device__ inline void gload16(const void* g, void* l) {
    __builtin_amdgcn_global_load_lds((const __attribute__((address_space(1))) void*)g,
                                     (__attribute__((address_space(3))) void*)l,
                                     16, 0, 0);
}

// Round-2 structure + double-buffered LDS = ONE barrier per k-tile.
// Per iteration t:  issue A-loads(t+1) & B-DMA(t+1 -> nxt)   [no waits]
//                   compute(t) from cur                       [covers latency]
//                   convert + ds_write A(t+1 -> nxt)          [vmcnt wait lands here]
//                   __syncthreads()                           [drain is a no-op by now]
// Safety: the end-of-iter barrier means all waves finished reading `nxt`
// (iteration t-1's compute buffer) before iteration t writes it.
__global__ __launch_bounds__(256, 4) void gemm_db(const float* __restrict__ X,
                                                  const unsigned short* __restrict__ Bt,
                                                  const float* __restrict__ bias,
                                                  float* __restrict__ C) {
    __shared__ unsigned short As[2][BM * BK];  // 2 x 8 KiB
    __shared__ unsigned short Bs[2][BN * BK];  // 2 x 8 KiB

    const int tid = threadIdx.x;
    const int wave = tid >> 6;
    const int lane = tid & 63;
    const int bid = blockIdx.x;
    const int bm = bid & 127;   // bm-fastest: the 8 bn-sharers of an X-stripe share an XCD
    const int bn = bid >> 7;
    const int wm = (wave >> 1) * 64;
    const int wn = (wave & 1) * 64;
    const int fr = lane & 15;
    const int fq = lane >> 4;
    const int fk = fq * 8;

    // ---- B staging map (proven round-1 global_load_lds chunk pattern) ----
    const int cw0 = wave, cw1 = wave + 4;      // 1-KiB chunks = 16 rows each
    const int brow0 = cw0 * 16 + (lane >> 2);
    const int brow1 = cw1 * 16 + (lane >> 2);
    const int bcol = (lane & 3) * 8;
    const unsigned short* gB0 = Bt + (size_t)(bn * BN + brow0) * Kdim + bcol;
    const unsigned short* gB1 = Bt + (size_t)(bn * BN + brow1) * Kdim + bcol;

    // ---- A staging map (fp32 wave-coalesced loads -> bf16 -> LDS) ----
    const int arow = tid >> 3;     // 0..31, plus u*32
    const int acol4 = tid & 7;     // float4 index within the 32-col tile
    const float* gA = X + (size_t)(bm * BM + arow) * Kdim + acol4 * 4;

    f32x4 acc[4][4] = {};
    f32x4 av[4];  // single-buffered: loaded and consumed within one iteration

    // ---- Prologue: stage tile 0 into buffer 0 (one exposed wait) ----
#pragma unroll
    for (int u = 0; u < 4; ++u)
        av[u] = *(const f32x4*)(gA + (size_t)u * 32 * Kdim);
    gload16(gB0, &Bs[0][cw0 * 512 + lane * 8]);
    gload16(gB1, &Bs[0][cw1 * 512 + lane * 8]);
#pragma unroll
    for (int u = 0; u < 4; ++u) {
        uint2 w;
        w.x = pkbf(av[u][0], av[u][1]);
        w.y = pkbf(av[u][2], av[u][3]);
        *(uint2*)(&As[0][(arow + u * 32) * BK + acol4 * 4]) = w;
    }
    __syncthreads();

    for (int t = 0; t < NT; ++t) {
        const int cur = t & 1, nxt = cur ^ 1;
        const bool pf = (t + 1 < NT);
        // 1) issue next tile's loads (no waits yet)
        if (pf) {
            const int kt = (t + 1) * BK;
#pragma unroll
            for (int u = 0; u < 4; ++u)
                av[u] = *(const f32x4*)(gA + (size_t)u * 32 * Kdim + kt);
            gload16(gB0 + kt, &Bs[nxt][cw0 * 512 + lane * 8]);
            gload16(gB1 + kt, &Bs[nxt][cw1 * 512 + lane * 8]);
        }
        // 2) compute current tile (covers the load latency in-wave)
        bf16x8 af[4], bfr[4];
#pragma unroll
        for (int i = 0; i < 4; ++i)
            af[i] = *(const bf16x8*)(&As[cur][(wm + i * 16 + fr) * BK + fk]);
#pragma unroll
        for (int j = 0; j < 4; ++j)
            bfr[j] = *(const bf16x8*)(&Bs[cur][(wn + j * 16 + fr) * BK + fk]);
#pragma unroll
        for (int i = 0; i < 4; ++i)
#pragma unroll
            for (int j = 0; j < 4; ++j)
                acc[i][j] = __builtin_amdgcn_mfma_f32_16x16x32_bf16(af[i], bfr[j], acc[i][j], 0, 0, 0);
        // 3) convert + write next A tile (first use of av -> vmcnt wait here)
        if (pf) {
#pragma unroll
            for (int u = 0; u < 4; ++u) {
                uint2 w;
                w.x = pkbf(av[u][0], av[u][1]);
                w.y = pkbf(av[u][2], av[u][3]);
                *(uint2*)(&As[nxt][(arow + u * 32) * BK + acol4 * 4]) = w;
            }
        }
        // 4) one barrier: B-DMA/A-writes visible; nxt's readers provably done
        __syncthreads();
    }

    // Epilogue: C/D layout col = lane&15, row = (lane>>4)*4 + reg  [m89-verified]
#pragma unroll
    for (int j = 0; j < 4; ++j) {
        const int col = bn * BN + wn + j * 16 + fr;
        const float bv = bias[col];
#pragma unroll
        for (int i = 0; i < 4; ++i) {
            const int row = bm * BM + wm + i * 16 + fq * 4;
            float* pc = C + (size_t)row * Ndim + col;
#pragma unroll
            for (int r = 0; r < 4; ++r)
                pc[(size_t)r * Ndim] = acc[i][j][r] + bv;
        }
    }
}

extern "C" void kernel_launch(void* const* d_in, const int* in_sizes, int n_in,
                              void* d_out, int out_size, void* d_ws, size_t ws_size,
                              hipStream_t stream) {
    // inputs: x, cond, mask, W_shared, W_expert, W_gate, bias
    const float* x    = (const float*)d_in[0];
    const float* Wsh  = (const float*)d_in[3];
    const float* Wex  = (const float*)d_in[4];
    const float* bias = (const float*)d_in[6];
    float* out = (float*)d_out;

    unsigned short* Wbf = (unsigned short*)d_ws;  // 1024*1024 bf16 = 2 MiB

    hipLaunchKernelGGL(cvt_w_kernel, dim3((Ndim * Kdim) / (256 * 8)), dim3(256), 0, stream,
                       Wsh, Wex, Wbf);
    hipLaunchKernelGGL(gemm_db, dim3((Mdim / BM) * (Ndim / BN)), dim3(256), 0, stream,
                       x, Wbf, bias, out);
}